// Round 7
// baseline (295.527 us; speedup 1.0000x reference)
//
#include <hip/hip_runtime.h>
#include <hip/hip_cooperative_groups.h>

namespace cg = cooperative_groups;

// SemanticCaps dynamic routing, fp32. B=128, J=10, K=1152, M=16, I=8.
// R7: ONE cooperative kernel (grid 256 x 512, 1 block/CU co-resident).
//  - Ws slice (9 k x all j, 51.8 KB) staged to LDS ONCE for all 3 iterations.
//  - x transposed once to a block-PRIVATE global slice xT[k][i][b] (no sync).
//  - thread = (b, m-quad); j serial; u[10][4], e[10], s[10][4], v[10][4] in
//    registers -> no per-k barriers, no u recompute, no c tensor.
//  - b-logit algebra: b after t iters = u.(v0+..+v_{t-1}).
//  - per-k-half partials sp[tile:256][j][b][m]; fold+squash by 81920 threads.
//  - 3 separate sp buffers (each written once, read once) -> no stale-L2 reuse.
// ws (floats): xT 1,179,648 | spA/B/C 3x5,242,880 | v0 20,480 | vsum 20,480

#define B_ 128
#define J_ 10
#define K_ 1152
#define M_ 16
#define KT 9
#define NV (J_ * B_ * M_)          // 20480 (= elements per sp tile)
#define SPN (256 * NV)             // per sp buffer

__device__ __forceinline__ float dot8(const float4 w0, const float4 w1,
                                      const float* xr) {
    return w0.x * xr[0] + w0.y * xr[1] + w0.z * xr[2] + w0.w * xr[3]
         + w1.x * xr[4] + w1.y * xr[5] + w1.z * xr[6] + w1.w * xr[7];
}

// fold 256 tile-partials for value v=(j*128+b)*16+m, squash, emit.
// FMODE 0: dst=v0 (S*=0.1)  1: dst=vsum=v0+squash  2: dst=out[b][j][m]
__device__ __forceinline__ void fold_squash(const float* __restrict__ sp, int gid,
                                            int FMODE, const float* __restrict__ v0b,
                                            float* __restrict__ dst) {
    if (gid < NV * 4) {
        const int v = gid >> 2, part = gid & 3;
        const float* p = sp + (size_t)part * 64 * NV + v;
        float S = 0.f;
#pragma unroll 8
        for (int tt = 0; tt < 64; ++tt) S += p[(size_t)tt * NV];
        S += __shfl_xor(S, 1, 64);          // combine 4 part-lanes (gid bits 0-1)
        S += __shfl_xor(S, 2, 64);
        if (FMODE == 0) S *= 0.1f;
        float sq = S * S;                   // sum over m (gid bits 2-5)
        sq += __shfl_xor(sq, 4, 64);
        sq += __shfl_xor(sq, 8, 64);
        sq += __shfl_xor(sq, 16, 64);
        sq += __shfl_xor(sq, 32, 64);
        const float n = sqrtf(sq);
        float vv = S * (n / (1.f + sq));
        if (FMODE == 1) vv += v0b[v];
        if ((gid & 3) == 0) {
            if (FMODE == 2) {
                const int m = v & 15, bb = (v >> 4) & 127, j = v >> 11;
                dst[((size_t)bb * J_ + j) * M_ + m] = vv;
            } else {
                dst[v] = vv;
            }
        }
    }
}

__global__ __launch_bounds__(512, 2)
void caps_kernel(const float* __restrict__ x, const float* __restrict__ Ws,
                 float* __restrict__ out, float* __restrict__ xT,
                 float* __restrict__ spA, float* __restrict__ spB,
                 float* __restrict__ spC, float* __restrict__ v0buf,
                 float* __restrict__ vsumbuf) {
    cg::grid_group grid = cg::this_grid();
    __shared__ float lds[12960];            // 51.84 KB (aliased: xpose tile, then Ws)

    const int t   = threadIdx.x;
    const int blk = blockIdx.x;
    const int kt  = blk >> 1, bg = blk & 1;
    const int k0  = kt * KT;
    const int b0  = bg * 64;

    // ---- phase 0: block-private x transpose -> xT[k][i][b] (global) ----
    {
        float* tile = lds;                   // [64][73] padded
        for (int l = t; l < 64 * 18; l += 512) {
            const int bl = l / 18, r = l - bl * 18;
            const int kl = r >> 1, ih = (r & 1) * 4;
            const float4 vx = *(const float4*)(x + ((size_t)(b0 + bl) * K_ + k0 + kl) * 8 + ih);
            float* d = tile + bl * 73 + kl * 8 + ih;
            d[0] = vx.x; d[1] = vx.y; d[2] = vx.z; d[3] = vx.w;
        }
        __syncthreads();
        for (int l = t; l < KT * 8 * 64; l += 512) {
            const int kl = l >> 9, rem = l & 511;
            const int i = rem >> 6, bl = rem & 63;
            xT[((size_t)(k0 + kl) * 8 + i) * B_ + b0 + bl] = tile[bl * 73 + kl * 8 + i];
        }
        __syncthreads();
    }

    // ---- phase 0b: stage Ws[all j][k0..k0+8][16m][8i] into padded LDS ----
    float4* ws4 = (float4*)lds;              // [kl]*360 + [j]*36 + [mq]*9 + r
    {
        const float4* wsg = (const float4*)Ws;
        for (int l = t; l < 2880; l += 512) {
            const int kl = l / 320, rem = l - kl * 320;
            const int j = rem >> 5, c = rem & 31;
            ws4[kl * 360 + j * 36 + (c >> 3) * 9 + (c & 7)] =
                wsg[((size_t)j * K_ + k0 + kl) * 32 + c];
        }
        __syncthreads();
    }

    const int wv   = t >> 6, lane = t & 63;
    const int kh   = wv & 1, bsg = wv >> 1;
    const int mq   = lane >> 4, bl = lane & 15;
    const int b    = b0 + bsg * 16 + bl;
    const int kkb  = kh ? 5 : 0, kke = kh ? 9 : 5;
    const int tile_id = kt * 2 + kh;
    const int gid  = blk * 512 + t;

    auto loadx = [&](float* dst, int kk) {
        const float* xp = xT + ((size_t)(k0 + kk) * 8) * B_ + b;
#pragma unroll
        for (int i = 0; i < 8; ++i) dst[i] = xp[(size_t)i * B_];
    };
    auto store_sp = [&](float* sp, const float s[J_][4]) {
#pragma unroll
        for (int j = 0; j < J_; ++j) {
            float4 o; o.x = s[j][0]; o.y = s[j][1]; o.z = s[j][2]; o.w = s[j][3];
            *(float4*)(sp + (((size_t)tile_id * J_ + j) * B_ + b) * M_ + mq * 4) = o;
        }
    };

    // ================= iteration 0: c uniform =================
    {
        float s[J_][4] = {};
        float xn[8];
        loadx(xn, kkb);
        for (int kk = kkb; kk < kke; ++kk) {
            float xr[8];
#pragma unroll
            for (int i = 0; i < 8; ++i) xr[i] = xn[i];
            if (kk + 1 < kke) loadx(xn, kk + 1);
#pragma unroll
            for (int j = 0; j < J_; ++j) {
                const float4* wq = ws4 + kk * 360 + j * 36 + mq * 9;
#pragma unroll
                for (int p2 = 0; p2 < 4; ++p2)
                    s[j][p2] += dot8(wq[2 * p2], wq[2 * p2 + 1], xr);
            }
        }
        store_sp(spA, s);
    }
    grid.sync();
    fold_squash(spA, gid, 0, nullptr, v0buf);
    grid.sync();

    // ================= iterations 1 & 2 (softmax routing) =================
#pragma unroll 1
    for (int it = 0; it < 2; ++it) {
        const float* vbuf = (it == 0) ? v0buf : vsumbuf;
        float* sp = (it == 0) ? spB : spC;

        float vj[J_][4];
#pragma unroll
        for (int j = 0; j < J_; ++j) {
            const float4 q = *(const float4*)(vbuf + ((size_t)j * B_ + b) * M_ + mq * 4);
            vj[j][0] = q.x; vj[j][1] = q.y; vj[j][2] = q.z; vj[j][3] = q.w;
        }

        float s[J_][4] = {};
        float xn[8];
        loadx(xn, kkb);
        for (int kk = kkb; kk < kke; ++kk) {
            float xr[8];
#pragma unroll
            for (int i = 0; i < 8; ++i) xr[i] = xn[i];
            if (kk + 1 < kke) loadx(xn, kk + 1);

            float u[J_][4], e[J_], den = 0.f;
#pragma unroll
            for (int j = 0; j < J_; ++j) {
                const float4* wq = ws4 + kk * 360 + j * 36 + mq * 9;
                float lg = 0.f;
#pragma unroll
                for (int p2 = 0; p2 < 4; ++p2) {
                    u[j][p2] = dot8(wq[2 * p2], wq[2 * p2 + 1], xr);
                    lg += u[j][p2] * vj[j][p2];
                }
                lg += __shfl_xor(lg, 16, 64);   // reduce over mq lanes
                lg += __shfl_xor(lg, 32, 64);
                e[j] = __expf(lg);
                den += e[j];
            }
            const float rden = 1.f / den;
#pragma unroll
            for (int j = 0; j < J_; ++j) {
                const float c = e[j] * rden;
#pragma unroll
                for (int p2 = 0; p2 < 4; ++p2) s[j][p2] += c * u[j][p2];
            }
        }
        store_sp(sp, s);
        grid.sync();
        if (it == 0) {
            fold_squash(spB, gid, 1, v0buf, vsumbuf);
            grid.sync();
        } else {
            fold_squash(spC, gid, 2, nullptr, out);
        }
    }
}

extern "C" void kernel_launch(void* const* d_in, const int* in_sizes, int n_in,
                              void* d_out, int out_size, void* d_ws, size_t ws_size,
                              hipStream_t stream) {
    const float* x  = (const float*)d_in[0];   // [128][1152][8]
    const float* Ws = (const float*)d_in[1];   // [10][1152][16][8]
    float* out = (float*)d_out;                // [128][10][16]

    float* xT  = (float*)d_ws;                 // 1,179,648 floats
    float* spA = xT + (size_t)K_ * 8 * B_;
    float* spB = spA + SPN;
    float* spC = spB + SPN;
    float* v0b = spC + SPN;
    float* vsb = v0b + NV;

    void* args[] = {(void*)&x, (void*)&Ws, (void*)&out, (void*)&xT,
                    (void*)&spA, (void*)&spB, (void*)&spC, (void*)&v0b, (void*)&vsb};
    hipLaunchCooperativeKernel((const void*)caps_kernel, dim3(256), dim3(512),
                               args, 0, stream);
}

// Round 8
// 291.210 us; speedup vs baseline: 1.0148x; 1.0148x over previous
//
#include <hip/hip_runtime.h>
#include <hip/hip_cooperative_groups.h>

namespace cg = cooperative_groups;

// SemanticCaps dynamic routing, fp32. B=128, J=10, K=1152, M=16, I=8.
// R8: R7 cooperative single-kernel + amdgpu_waves_per_eu(2,2).
// R7 post-mortem: VGPR_Count=96 vs ~146-float live set (u[10][4], s[10][4],
// vj[10][4], xr/xn, e[10]) -> compiler spilled to scratch chasing default
// occupancy; VALUBusy 12%. At our fixed 2 waves/EU (1 block/CU, 8 waves),
// 256 VGPR/wave is available — pin it so the allocator uses it.
//  - Ws slice (9 k x all j, 51.8 KB) staged to LDS ONCE for all 3 iterations.
//  - x transposed once to a block-PRIVATE global slice xT[k][i][b].
//  - thread = (b, m-quad); j serial; u/e/s/v all in registers; no per-k
//    barriers, no u recompute, no c tensor.
//  - b-logit algebra: b after t iters = u.(v0+..+v_{t-1}).
//  - per-k-half partials sp[tile:256][j][b][m]; fold+squash by 81920 threads.
//  - 3 separate sp buffers (each written once, read once).
// ws (floats): xT 1,179,648 | spA/B/C 3x5,242,880 | v0 20,480 | vsum 20,480

#define B_ 128
#define J_ 10
#define K_ 1152
#define M_ 16
#define KT 9
#define NV (J_ * B_ * M_)          // 20480 (= elements per sp tile)
#define SPN (256 * NV)             // per sp buffer

__device__ __forceinline__ float dot8(const float4 w0, const float4 w1,
                                      const float* xr) {
    return w0.x * xr[0] + w0.y * xr[1] + w0.z * xr[2] + w0.w * xr[3]
         + w1.x * xr[4] + w1.y * xr[5] + w1.z * xr[6] + w1.w * xr[7];
}

// fold 256 tile-partials for value v=(j*128+b)*16+m, squash, emit.
// FMODE 0: dst=v0 (S*=0.1)  1: dst=vsum=v0+squash  2: dst=out[b][j][m]
__device__ __forceinline__ void fold_squash(const float* __restrict__ sp, int gid,
                                            int FMODE, const float* __restrict__ v0b,
                                            float* __restrict__ dst) {
    if (gid < NV * 4) {
        const int v = gid >> 2, part = gid & 3;
        const float* p = sp + (size_t)part * 64 * NV + v;
        float S = 0.f;
#pragma unroll 16
        for (int tt = 0; tt < 64; ++tt) S += p[(size_t)tt * NV];
        S += __shfl_xor(S, 1, 64);          // combine 4 part-lanes (gid bits 0-1)
        S += __shfl_xor(S, 2, 64);
        if (FMODE == 0) S *= 0.1f;
        float sq = S * S;                   // sum over m (gid bits 2-5)
        sq += __shfl_xor(sq, 4, 64);
        sq += __shfl_xor(sq, 8, 64);
        sq += __shfl_xor(sq, 16, 64);
        sq += __shfl_xor(sq, 32, 64);
        const float n = sqrtf(sq);
        float vv = S * (n / (1.f + sq));
        if (FMODE == 1) vv += v0b[v];
        if ((gid & 3) == 0) {
            if (FMODE == 2) {
                const int m = v & 15, bb = (v >> 4) & 127, j = v >> 11;
                dst[((size_t)bb * J_ + j) * M_ + m] = vv;
            } else {
                dst[v] = vv;
            }
        }
    }
}

__global__ __launch_bounds__(512)
__attribute__((amdgpu_waves_per_eu(2, 2)))
void caps_kernel(const float* __restrict__ x, const float* __restrict__ Ws,
                 float* __restrict__ out, float* __restrict__ xT,
                 float* __restrict__ spA, float* __restrict__ spB,
                 float* __restrict__ spC, float* __restrict__ v0buf,
                 float* __restrict__ vsumbuf) {
    cg::grid_group grid = cg::this_grid();
    __shared__ float lds[12960];            // 51.84 KB (aliased: xpose tile, then Ws)

    const int t   = threadIdx.x;
    const int blk = blockIdx.x;
    const int kt  = blk >> 1, bg = blk & 1;
    const int k0  = kt * KT;
    const int b0  = bg * 64;

    // ---- phase 0: block-private x transpose -> xT[k][i][b] (global) ----
    {
        float* tile = lds;                   // [64][73] padded
        for (int l = t; l < 64 * 18; l += 512) {
            const int bl = l / 18, r = l - bl * 18;
            const int kl = r >> 1, ih = (r & 1) * 4;
            const float4 vx = *(const float4*)(x + ((size_t)(b0 + bl) * K_ + k0 + kl) * 8 + ih);
            float* d = tile + bl * 73 + kl * 8 + ih;
            d[0] = vx.x; d[1] = vx.y; d[2] = vx.z; d[3] = vx.w;
        }
        __syncthreads();
        for (int l = t; l < KT * 8 * 64; l += 512) {
            const int kl = l >> 9, rem = l & 511;
            const int i = rem >> 6, bl = rem & 63;
            xT[((size_t)(k0 + kl) * 8 + i) * B_ + b0 + bl] = tile[bl * 73 + kl * 8 + i];
        }
        __syncthreads();
    }

    // ---- phase 0b: stage Ws[all j][k0..k0+8][16m][8i] into padded LDS ----
    float4* ws4 = (float4*)lds;              // [kl]*360 + [j]*36 + [mq]*9 + r
    {
        const float4* wsg = (const float4*)Ws;
        for (int l = t; l < 2880; l += 512) {
            const int kl = l / 320, rem = l - kl * 320;
            const int j = rem >> 5, c = rem & 31;
            ws4[kl * 360 + j * 36 + (c >> 3) * 9 + (c & 7)] =
                wsg[((size_t)j * K_ + k0 + kl) * 32 + c];
        }
        __syncthreads();
    }

    const int wv   = t >> 6, lane = t & 63;
    const int kh   = wv & 1, bsg = wv >> 1;
    const int mq   = lane >> 4, bl = lane & 15;
    const int b    = b0 + bsg * 16 + bl;
    const int kkb  = kh ? 5 : 0, kke = kh ? 9 : 5;
    const int tile_id = kt * 2 + kh;
    const int gid  = blk * 512 + t;

    auto loadx = [&](float* dst, int kk) {
        const float* xp = xT + ((size_t)(k0 + kk) * 8) * B_ + b;
#pragma unroll
        for (int i = 0; i < 8; ++i) dst[i] = xp[(size_t)i * B_];
    };
    auto store_sp = [&](float* sp, const float s[J_][4]) {
#pragma unroll
        for (int j = 0; j < J_; ++j) {
            float4 o; o.x = s[j][0]; o.y = s[j][1]; o.z = s[j][2]; o.w = s[j][3];
            *(float4*)(sp + (((size_t)tile_id * J_ + j) * B_ + b) * M_ + mq * 4) = o;
        }
    };

    // ================= iteration 0: c uniform =================
    {
        float s[J_][4] = {};
        float xn[8];
        loadx(xn, kkb);
        for (int kk = kkb; kk < kke; ++kk) {
            float xr[8];
#pragma unroll
            for (int i = 0; i < 8; ++i) xr[i] = xn[i];
            if (kk + 1 < kke) loadx(xn, kk + 1);
#pragma unroll
            for (int j = 0; j < J_; ++j) {
                const float4* wq = ws4 + kk * 360 + j * 36 + mq * 9;
#pragma unroll
                for (int p2 = 0; p2 < 4; ++p2)
                    s[j][p2] += dot8(wq[2 * p2], wq[2 * p2 + 1], xr);
            }
        }
        store_sp(spA, s);
    }
    grid.sync();
    fold_squash(spA, gid, 0, nullptr, v0buf);
    grid.sync();

    // ================= iterations 1 & 2 (softmax routing) =================
#pragma unroll 1
    for (int it = 0; it < 2; ++it) {
        const float* vbuf = (it == 0) ? v0buf : vsumbuf;
        float* sp = (it == 0) ? spB : spC;

        float vj[J_][4];
#pragma unroll
        for (int j = 0; j < J_; ++j) {
            const float4 q = *(const float4*)(vbuf + ((size_t)j * B_ + b) * M_ + mq * 4);
            vj[j][0] = q.x; vj[j][1] = q.y; vj[j][2] = q.z; vj[j][3] = q.w;
        }

        float s[J_][4] = {};
        float xn[8];
        loadx(xn, kkb);
        for (int kk = kkb; kk < kke; ++kk) {
            float xr[8];
#pragma unroll
            for (int i = 0; i < 8; ++i) xr[i] = xn[i];
            if (kk + 1 < kke) loadx(xn, kk + 1);

            float u[J_][4], e[J_], den = 0.f;
#pragma unroll
            for (int j = 0; j < J_; ++j) {
                const float4* wq = ws4 + kk * 360 + j * 36 + mq * 9;
                float lg = 0.f;
#pragma unroll
                for (int p2 = 0; p2 < 4; ++p2) {
                    u[j][p2] = dot8(wq[2 * p2], wq[2 * p2 + 1], xr);
                    lg += u[j][p2] * vj[j][p2];
                }
                lg += __shfl_xor(lg, 16, 64);   // reduce over mq lanes
                lg += __shfl_xor(lg, 32, 64);
                e[j] = __expf(lg);
                den += e[j];
            }
            const float rden = 1.f / den;
#pragma unroll
            for (int j = 0; j < J_; ++j) {
                const float c = e[j] * rden;
#pragma unroll
                for (int p2 = 0; p2 < 4; ++p2) s[j][p2] += c * u[j][p2];
            }
        }
        store_sp(sp, s);
        grid.sync();
        if (it == 0) {
            fold_squash(spB, gid, 1, v0buf, vsumbuf);
            grid.sync();
        } else {
            fold_squash(spC, gid, 2, nullptr, out);
        }
    }
}

extern "C" void kernel_launch(void* const* d_in, const int* in_sizes, int n_in,
                              void* d_out, int out_size, void* d_ws, size_t ws_size,
                              hipStream_t stream) {
    const float* x  = (const float*)d_in[0];   // [128][1152][8]
    const float* Ws = (const float*)d_in[1];   // [10][1152][16][8]
    float* out = (float*)d_out;                // [128][10][16]

    float* xT  = (float*)d_ws;                 // 1,179,648 floats
    float* spA = xT + (size_t)K_ * 8 * B_;
    float* spB = spA + SPN;
    float* spC = spB + SPN;
    float* v0b = spC + SPN;
    float* vsb = v0b + NV;

    void* args[] = {(void*)&x, (void*)&Ws, (void*)&out, (void*)&xT,
                    (void*)&spA, (void*)&spB, (void*)&spC, (void*)&v0b, (void*)&vsb};
    hipLaunchCooperativeKernel((const void*)caps_kernel, dim3(256), dim3(512),
                               args, 0, stream);
}

// Round 9
// 194.039 us; speedup vs baseline: 1.5230x; 1.5008x over previous
//
#include <hip/hip_runtime.h>

// SemanticCaps dynamic routing, fp32. B=128, J=10, K=1152, M=16, I=8.
// R9: materialized u_hat, every kernel engineered to a bandwidth roofline.
//  - u_hat layout [j][k][q:mquad][b][r:4] -> writer (lane=b) and reader
//    (lane=bl*4+mq) both issue consecutive-float4 wave transactions.
//  - uhat kernel: Ws slice in LDS once per (j,ktile), served to all 128 b
//    via wave-uniform broadcast reads; iter-0 sum fused (softmax(0)=0.1).
//  - iter kernel: single pass over u_hat; 10 j-loads issued before use;
//    softmax across mq via 2 shuffles; u kept in regs within one k-step.
//  - b-logit algebra: logits after t iters = u.(v0+..+v_{t-1}).
// ws (floats): u_hat 23,592,960 | sp 5,898,240 | v0 20,480 | vsum 20,480

#define B_ 128
#define J_ 10
#define K_ 1152
#define NT1 144           // uhat tiles (8 k each) = s0 partial tiles
#define NT2 288           // iter tiles (4 k each)

__device__ __forceinline__ float dot8(const float4 w0, const float4 w1,
                                      const float4 xa, const float4 xb) {
    return w0.x * xa.x + w0.y * xa.y + w0.z * xa.z + w0.w * xa.w
         + w1.x * xb.x + w1.y * xb.y + w1.z * xb.z + w1.w * xb.w;
}

// ---------------- K1: u_hat + fused iter-0 partials -------------------------
// grid (144 kt, 10 j), 128 thr (thread = b, 2 waves), 8 k serial.
__global__ __launch_bounds__(128)
void uhat_kernel(const float* __restrict__ x, const float* __restrict__ Ws,
                 float* __restrict__ u_hat, float* __restrict__ sp) {
    __shared__ float4 wlds[256];            // Ws[j][k0..k0+7][16m][8i], 4 KB
    const int b  = threadIdx.x;
    const int kt = blockIdx.x, j = blockIdx.y;
    const int k0 = kt * 8;

    const float4* wg = (const float4*)(Ws + ((size_t)j * K_ + k0) * 128);
    wlds[b]       = wg[b];
    wlds[b + 128] = wg[b + 128];
    __syncthreads();

    const float* xp = x + ((size_t)b * K_ + k0) * 8;
    float4* uh = (float4*)u_hat;

    float s0[16];
#pragma unroll
    for (int m = 0; m < 16; ++m) s0[m] = 0.f;

    float4 xa = *(const float4*)xp;
    float4 xb = *(const float4*)(xp + 4);
#pragma unroll 1
    for (int kk = 0; kk < 8; ++kk) {
        float4 na, nb;
        if (kk < 7) {                        // prefetch next k
            na = *(const float4*)(xp + (kk + 1) * 8);
            nb = *(const float4*)(xp + (kk + 1) * 8 + 4);
        }
        float u[16];
#pragma unroll
        for (int m = 0; m < 16; ++m)
            u[m] = dot8(wlds[kk * 32 + m * 2], wlds[kk * 32 + m * 2 + 1], xa, xb);

        const size_t kb = ((size_t)j * K_ + k0 + kk) * 4;
#pragma unroll
        for (int q = 0; q < 4; ++q) {       // lanes = consecutive b -> contiguous
            float4 o;
            o.x = u[4 * q]; o.y = u[4 * q + 1]; o.z = u[4 * q + 2]; o.w = u[4 * q + 3];
            uh[(kb + q) * 128 + b] = o;
        }
#pragma unroll
        for (int m = 0; m < 16; ++m) s0[m] += u[m];
        xa = na; xb = nb;
    }

    float4* sp4 = (float4*)sp;              // s0 partial: tile = kt (144 tiles)
#pragma unroll
    for (int q = 0; q < 4; ++q) {
        float4 o;
        o.x = s0[4 * q]; o.y = s0[4 * q + 1]; o.z = s0[4 * q + 2]; o.w = s0[4 * q + 3];
        sp4[(((size_t)kt * J_ + j) * 4 + q) * 128 + b] = o;
    }
}

// ---------------- K2: routing pass (streams u_hat once) ---------------------
// grid (288 kt, 2 bg), 256 thr = 4 waves; lane = bl*4+mq; 4 k serial.
__global__ __launch_bounds__(256)
__attribute__((amdgpu_waves_per_eu(2)))
void iter_kernel(const float* __restrict__ u_hat, const float* __restrict__ vin,
                 float* __restrict__ sp) {
    const int t = threadIdx.x, w = t >> 6, lane = t & 63;
    const int bl = lane >> 2, mq = lane & 3;
    const int kt = blockIdx.x, bg = blockIdx.y;
    const int b  = bg * 64 + w * 16 + bl;

    const float4* u4 = (const float4*)u_hat;
    const float4* v4 = (const float4*)vin;

    float4 vj[J_], s[J_];
#pragma unroll
    for (int j = 0; j < J_; ++j) {
        vj[j] = v4[((size_t)j * 4 + mq) * 128 + b];
        s[j].x = 0.f; s[j].y = 0.f; s[j].z = 0.f; s[j].w = 0.f;
    }

#pragma unroll 1
    for (int kk = 0; kk < 4; ++kk) {
        const int k = kt * 4 + kk;
        float4 uu[J_];
#pragma unroll
        for (int j = 0; j < J_; ++j)        // 10 independent loads in flight
            uu[j] = u4[((size_t)(j * K_ + k) * 4 + mq) * 128 + b];

        float e[J_], den = 0.f;
#pragma unroll
        for (int j = 0; j < J_; ++j) {
            float lg = uu[j].x * vj[j].x + uu[j].y * vj[j].y
                     + uu[j].z * vj[j].z + uu[j].w * vj[j].w;
            lg += __shfl_xor(lg, 1, 64);    // combine 4 mq lanes -> full 16-m dot
            lg += __shfl_xor(lg, 2, 64);
            e[j] = __expf(lg);
            den += e[j];
        }
        const float inv = 1.f / den;
#pragma unroll
        for (int j = 0; j < J_; ++j) {
            const float c = e[j] * inv;
            s[j].x += c * uu[j].x; s[j].y += c * uu[j].y;
            s[j].z += c * uu[j].z; s[j].w += c * uu[j].w;
        }
    }

    float4* sp4 = (float4*)sp;
#pragma unroll
    for (int j = 0; j < J_; ++j)
        sp4[(((size_t)kt * J_ + j) * 4 + mq) * 128 + b] = s[j];
}

// ---------------- squash: fold tile partials, emit v ------------------------
// 5120 threads; thread = (j,b,q) handles one float4.
// SM 0: v0 = squash(0.1*S)  SM 1: vsum = v0 + squash(S)  SM 2: out = squash(S)
template <int SM>
__global__ __launch_bounds__(128)
void squash_kernel(const float* __restrict__ sp, int ntiles,
                   const float* __restrict__ v0, float* __restrict__ dst) {
    const int g = blockIdx.x * 128 + threadIdx.x;    // [0, 5120)
    const int q = g & 3, b = (g >> 2) & 127, j = g >> 9;
    const float4* sp4 = (const float4*)sp;

    float4 S; S.x = 0.f; S.y = 0.f; S.z = 0.f; S.w = 0.f;
#pragma unroll 8
    for (int tt = 0; tt < ntiles; ++tt) {
        const float4 p = sp4[(((size_t)tt * J_ + j) * 4 + q) * 128 + b];
        S.x += p.x; S.y += p.y; S.z += p.z; S.w += p.w;
    }
    if (SM == 0) { S.x *= 0.1f; S.y *= 0.1f; S.z *= 0.1f; S.w *= 0.1f; }

    float nq = S.x * S.x + S.y * S.y + S.z * S.z + S.w * S.w;
    nq += __shfl_xor(nq, 1, 64);            // q lives in lane bits 0-1
    nq += __shfl_xor(nq, 2, 64);
    const float n = sqrtf(nq);
    const float f = n / (1.f + nq);
    float4 V; V.x = S.x * f; V.y = S.y * f; V.z = S.z * f; V.w = S.w * f;

    if (SM == 1) {
        const float4 p = ((const float4*)v0)[((size_t)j * 4 + q) * 128 + b];
        V.x += p.x; V.y += p.y; V.z += p.z; V.w += p.w;
    }
    if (SM == 2) ((float4*)dst)[((size_t)b * J_ + j) * 4 + q] = V;   // out[b][j][m]
    else         ((float4*)dst)[((size_t)j * 4 + q) * 128 + b] = V;  // [j][q][b][r]
}

extern "C" void kernel_launch(void* const* d_in, const int* in_sizes, int n_in,
                              void* d_out, int out_size, void* d_ws, size_t ws_size,
                              hipStream_t stream) {
    const float* x  = (const float*)d_in[0];   // [128][1152][8]
    const float* Ws = (const float*)d_in[1];   // [10][1152][16][8]
    float* out = (float*)d_out;                // [128][10][16]

    float* u_hat = (float*)d_ws;                              // 23,592,960
    float* sp    = u_hat + (size_t)J_ * K_ * B_ * 16;         //  5,898,240
    float* v0    = sp + (size_t)NT2 * J_ * 4 * B_ * 4;        //     20,480
    float* vsum  = v0 + J_ * B_ * 16;                         //     20,480

    uhat_kernel<<<dim3(NT1, J_), 128, 0, stream>>>(x, Ws, u_hat, sp);
    squash_kernel<0><<<40, 128, 0, stream>>>(sp, NT1, nullptr, v0);

    iter_kernel<<<dim3(NT2, 2), 256, 0, stream>>>(u_hat, v0, sp);
    squash_kernel<1><<<40, 128, 0, stream>>>(sp, NT2, v0, vsum);

    iter_kernel<<<dim3(NT2, 2), 256, 0, stream>>>(u_hat, vsum, sp);
    squash_kernel<2><<<40, 128, 0, stream>>>(sp, NT2, nullptr, out);
}

// Round 10
// 159.427 us; speedup vs baseline: 1.8537x; 1.2171x over previous
//
#include <hip/hip_runtime.h>

// SemanticCaps dynamic routing, fp32. B=128, J=10, K=1152, M=16, I=8.
// R10: recompute design with the LDS pipe fixed. Diagnosis from R4-R8: every
// prior recompute read 16 B of W from LDS per 8 FMA per lane (8 B/FLOP vs the
// 0.5 B/FLOP LDS:VALU machine balance -> 16x oversubscribed, ~19us/iter floor).
// Fix: lane = (b-quad, m). The 16 m-lanes read distinct W chunks (stride-10
// pad, conflict-free) while 4 b-groups MULTICAST the same LDS addresses
// (same-address broadcast is free) -> 4x less unique LDS traffic, and all
// per-lane state (u[j], e[j], s[j], v[j]) collapses to 10 scalars each.
// k-outer / j-inner: x[8] loaded once per k (global, L1-hot, prefetched);
// logit via 4-shuffle m-reduce; softmax in regs; NO per-k barriers.
// Grid 128 ktiles x 2 bhalves = 256 blocks x 1024 thr = 1 block/CU (16 waves).
// W read ONCE per iter (5.9 MB). Partials sp[128][j][b][m], fully coalesced.
// b-logit algebra: logits after t iters = u.(v0+..+v_{t-1}) (b starts at 0).
// ws (floats): sp0/1/2 3x2,621,440 | v0 20,480 | vsum 20,480

#define B_ 128
#define J_ 10
#define K_ 1152
#define KT 9
#define NTL 128           // k-tiles
#define NV 20480          // J*B*M, one sp tile / one v buffer
#define WSTRIDE 10        // W m-stride in floats (8 + 2 pad); m*10%32 distinct

// MODE 0: c == 1 (iteration 0; the 0.1 is folded into squash<0>)
// MODE 1: c = softmax_j(u . vin)
template <int MODE>
__global__ __launch_bounds__(1024)
void iter_kernel(const float* __restrict__ x, const float* __restrict__ Ws,
                 const float* __restrict__ vin, float* __restrict__ sp) {
    __shared__ float wl[KT * 1600];          // [k][j][m][10] = 57.6 KB

    const int t  = threadIdx.x;
    const int kt = blockIdx.x, bh = blockIdx.y;
    const int k0 = kt * KT, b0 = bh * 64;

    // ---- stage W[all j][k0..k0+8][16m][8i] -> LDS, float2 granularity ----
    {
        float2* wl2 = (float2*)wl;
        const float2* wg2 = (const float2*)Ws;
        for (int l = t; l < 5760; l += 1024) {
            const int k = l / 640, r = l - k * 640;
            const int j = r >> 6, r2 = r & 63, mm = r2 >> 2, i2 = r2 & 3;
            wl2[k * 800 + j * 80 + mm * 5 + i2] =
                wg2[((size_t)j * K_ + k0 + k) * 64 + mm * 4 + i2];
        }
    }

    const int m  = t & 15;                   // lane bits 0-3
    const int bq = (t >> 4) & 3;             // lane bits 4-5
    const int w  = t >> 6;
    const int b  = b0 + w * 4 + bq;

    float v[J_];
    if (MODE == 1) {
#pragma unroll
        for (int j = 0; j < J_; ++j)         // idx = base + lane: coalesced
            v[j] = vin[((size_t)j * B_ + b) * 16 + m];
    }
    __syncthreads();

    const float4* xg = (const float4*)x;
    auto load8 = [&](float* d, int kk) {
        const float4* p = xg + ((size_t)b * K_ + k0 + kk) * 2;
        const float4 a = p[0], c = p[1];
        d[0] = a.x; d[1] = a.y; d[2] = a.z; d[3] = a.w;
        d[4] = c.x; d[5] = c.y; d[6] = c.z; d[7] = c.w;
    };

    float s[J_];
#pragma unroll
    for (int j = 0; j < J_; ++j) s[j] = 0.f;

    float xr[8], xn[8];
    load8(xn, 0);
#pragma unroll 1
    for (int kk = 0; kk < KT; ++kk) {
#pragma unroll
        for (int i = 0; i < 8; ++i) xr[i] = xn[i];
        if (kk + 1 < KT) load8(xn, kk + 1);

        float uu[J_], ee[J_], den = 0.f;
#pragma unroll
        for (int j = 0; j < J_; ++j) {
            // 16 m-lanes: distinct banks (m*10%32 all distinct); 4 bq-groups
            // multicast the same addresses -> broadcast, no extra cycles.
            const float2* wp = (const float2*)(wl + kk * 1600 + j * 160 + m * WSTRIDE);
            const float2 wa = wp[0], wb = wp[1], wc = wp[2], wd = wp[3];
            const float u = wa.x * xr[0] + wa.y * xr[1] + wb.x * xr[2] + wb.y * xr[3]
                          + wc.x * xr[4] + wc.y * xr[5] + wd.x * xr[6] + wd.y * xr[7];
            if (MODE == 1) {
                uu[j] = u;
                float lg = u * v[j];
                lg += __shfl_xor(lg, 1, 64);   // reduce over m (lane bits 0-3)
                lg += __shfl_xor(lg, 2, 64);
                lg += __shfl_xor(lg, 4, 64);
                lg += __shfl_xor(lg, 8, 64);
                ee[j] = __expf(lg);
                den += ee[j];
            } else {
                s[j] += u;
            }
        }
        if (MODE == 1) {
            const float inv = 1.f / den;
#pragma unroll
            for (int j = 0; j < J_; ++j) s[j] += ee[j] * inv * uu[j];
        }
    }

#pragma unroll
    for (int j = 0; j < J_; ++j)             // idx = base + lane: coalesced
        sp[(((size_t)kt * J_ + j) * B_ + b) * 16 + m] = s[j];
}

// ---------- squash: fold 128 tile-partials, emit v ---------------------------
// value index g = (j*128+b)*16+m.
// SM 0: v0 = squash(0.1*S)  SM 1: vsum = v0 + squash(S)  SM 2: out = squash(S)
template <int SM>
__global__ __launch_bounds__(256)
void squash_kernel(const float* __restrict__ sp, const float* __restrict__ v0,
                   float* __restrict__ dst) {
    const int g = blockIdx.x * 256 + threadIdx.x;    // [0, 20480)
    float S = 0.f;
#pragma unroll 16
    for (int tt = 0; tt < NTL; ++tt) S += sp[(size_t)tt * NV + g];
    if (SM == 0) S *= 0.1f;
    float nq = S * S;                        // m = lane bits 0-3
    nq += __shfl_xor(nq, 1, 64);
    nq += __shfl_xor(nq, 2, 64);
    nq += __shfl_xor(nq, 4, 64);
    nq += __shfl_xor(nq, 8, 64);
    const float n = sqrtf(nq);
    float vv = S * (n / (1.f + nq));
    if (SM == 1) vv += v0[g];
    if (SM == 2) {
        const int m = g & 15, b = (g >> 4) & 127, j = g >> 11;
        dst[((size_t)b * J_ + j) * 16 + m] = vv;     // out[b][j][m]
    } else {
        dst[g] = vv;
    }
}

extern "C" void kernel_launch(void* const* d_in, const int* in_sizes, int n_in,
                              void* d_out, int out_size, void* d_ws, size_t ws_size,
                              hipStream_t stream) {
    const float* x  = (const float*)d_in[0];   // [128][1152][8]
    const float* Ws = (const float*)d_in[1];   // [10][1152][16][8]
    float* out = (float*)d_out;                // [128][10][16]

    float* sp0  = (float*)d_ws;                // 2,621,440 each
    float* sp1  = sp0 + (size_t)NTL * NV;
    float* sp2  = sp1 + (size_t)NTL * NV;
    float* v0   = sp2 + (size_t)NTL * NV;
    float* vsum = v0 + NV;

    const dim3 gi(NTL, 2);
    iter_kernel<0><<<gi, 1024, 0, stream>>>(x, Ws, nullptr, sp0);
    squash_kernel<0><<<80, 256, 0, stream>>>(sp0, nullptr, v0);

    iter_kernel<1><<<gi, 1024, 0, stream>>>(x, Ws, v0, sp1);
    squash_kernel<1><<<80, 256, 0, stream>>>(sp1, v0, vsum);

    iter_kernel<1><<<gi, 1024, 0, stream>>>(x, Ws, vsum, sp2);
    squash_kernel<2><<<80, 256, 0, stream>>>(sp2, nullptr, out);
}